// Round 1
// baseline (165.477 us; speedup 1.0000x reference)
//
#include <hip/hip_runtime.h>
#include <hip/hip_cooperative_groups.h>
#include <math.h>

namespace cg = cooperative_groups;

#define QHn 128
#define QWn 128
#define Qn  16384
#define Hn  64
#define Wn  64
#define Cn  64
#define Bn  4
#define HIDn 256
#define OUTn 1728   // C*9*3
#define PWPAD 28    // padded floats per channel (112 B, 16B-aligned stride)
#define PWSTRIDE (Cn * PWPAD)   // 1792 floats per phase
#define EPSf 1e-6f

// Reference-faithful coordinate math (fp32, same op order/rounding as jnp).
__device__ __forceinline__ void coord_math(const float* __restrict__ coord,
                                           const float* __restrict__ cell,
                                           int b, int q,
                                           int& iy, int& ix,
                                           float& rely, float& relx, float& rrev) {
    const size_t base = ((size_t)b * Qn + q) * 2;
    const float cy = coord[base + 0];
    const float cx = coord[base + 1];
    const float ey = cell[base + 0];
    const float ex = cell[base + 1];
    const float c_y = cy - ey * 0.5f;
    const float c_x = cx - ex * 0.5f;
    const float cqy = fminf(fmaxf(c_y + EPSf, -1.0f + EPSf), 1.0f - EPSf);
    const float cqx = fminf(fmaxf(c_x + EPSf, -1.0f + EPSf), 1.0f - EPSf);
    float fy = rintf(((cqy + 1.0f) * (float)Hn - 1.0f) * 0.5f);  // round-half-even
    float fx = rintf(((cqx + 1.0f) * (float)Wn - 1.0f) * 0.5f);
    fy = fminf(fmaxf(fy, 0.0f), (float)(Hn - 1));
    fx = fminf(fmaxf(fx, 0.0f), (float)(Wn - 1));
    iy = (int)fy;
    ix = (int)fx;
    const float qcy = -1.0f + 2.0f * fy / (float)Hn;
    const float qcx = -1.0f + 2.0f * fx / (float)Wn;
    rely = (c_y - qcy) * ((float)Hn * 0.5f);
    relx = (c_x - qcx) * ((float)Wn * 0.5f);
    rrev = ey * ((float)Hn * 0.5f);
}

// Fused cooperative kernel. grid=(8,8,4)=256 blocks (1/CU), block=256.
// Experiment: ZERO d_ws usage — the 28 KB pw scratch lives in the first 7168
// floats of `out`, guarded by two grid-wide barriers:
//   A: 108 blocks compute phase pw -> out[0..7168); all blocks stage patch LDS
//   grid.sync()  (pw visible everywhere)
//   B: every thread accumulates its output (pw via wave-uniform scalar loads)
//   grid.sync()  (all pw READS complete before any final out WRITE)
//   C: write final outputs (overwrites the scratch region with real results)
__global__ __launch_bounds__(256) void metasr_fused(
    const float* __restrict__ feat, const float* __restrict__ coord,
    const float* __restrict__ cell, const float* __restrict__ w1,
    const float* __restrict__ b1, const float* __restrict__ w2,
    const float* __restrict__ b2, float* out) {
    __shared__ float patch[Cn * 100];   // [c][10][10], 25.6 KB
    __shared__ float hdd[HIDn];         // pw-MLP hidden (pw blocks only)
    __shared__ float part[4 * 64];      // pw-MLP slice partials

    const int tid = threadIdx.x;
    const int bid = (int)blockIdx.x + ((int)blockIdx.y << 3) + ((int)blockIdx.z << 6);
    const int bz  = blockIdx.z;
    const int i0  = blockIdx.y * 8;     // LR tile origin
    const int j0  = blockIdx.x * 8;

    // ---- Stage A1: pw matrices (108 units = 27 t-chunks x 4 phases) ----
    if (bid < 108) {
        const int p      = bid & 3;
        const int tchunk = bid >> 2;
        const int py = p >> 1, px = p & 1;
        const int q  = py * QWn + px;   // representative query, batch 0

        int iy_, ix_; float rely, relx, rrev;
        coord_math(coord, cell, 0, q, iy_, ix_, rely, relx, rrev);

        {   // hidden layer: thread j computes hdd[j]
            const int j = tid;
            float h = b1[j] + rely * w1[j] + relx * w1[HIDn + j] + rrev * w1[2 * HIDn + j];
            hdd[j] = fmaxf(h, 0.0f);
        }
        __syncthreads();

        const int tloc  = tid & 63;
        const int slice = tid >> 6;
        const int t     = tchunk * 64 + tloc;   // 0..1727

        float s = 0.0f;
        const int j0h = slice * 64;
        #pragma unroll 16
        for (int jj = 0; jj < 64; ++jj)
            s = fmaf(hdd[j0h + jj], w2[(size_t)(j0h + jj) * OUTn + t], s);
        part[slice * 64 + tloc] = s;
        __syncthreads();

        if (tid < 64) {
            const int tt = tchunk * 64 + tid;
            float v = b2[tt] + part[tid] + part[64 + tid] + part[128 + tid] + part[192 + tid];
            const int c   = tt / 27;
            const int rem = tt - c * 27;
            out[p * PWSTRIDE + c * PWPAD + rem] = v;   // scratch region of out
        }
    }

    // ---- Stage A2: all blocks stage patch cube (zero-padded halo) ----
    for (int e = tid; e < Cn * 100; e += 256) {
        const int c  = e / 100;
        const int r  = e - c * 100;
        const int yy = r / 10;
        const int xx = r - yy * 10;
        const int gy = i0 - 1 + yy;
        const int gx = j0 - 1 + xx;
        float v = 0.0f;
        if ((unsigned)gy < (unsigned)Hn && (unsigned)gx < (unsigned)Wn)
            v = feat[(((size_t)bz * Cn + c) * Hn + gy) * Wn + gx];
        patch[e] = v;
    }

    cg::this_grid().sync();   // pw scratch globally visible; patch staged

    // ---- Stage B: thread -> HR pixel: wave = phase, lane = 8x8 LR pixel ----
    const int wv   = tid >> 6;
    const int lane = tid & 63;
    const int li   = lane >> 3, lj = lane & 7;
    const int Y = (i0 + li) * 2 + (wv >> 1);
    const int X = (j0 + lj) * 2 + (wv & 1);

    int iy, ix; float rely, relx, rrev;
    coord_math(coord, cell, bz, Y * QWn + X, iy, ix, rely, relx, rrev);
    (void)rrev;
    int pc = ((rely > 0.25f) ? 2 : 0) + ((relx > 0.25f) ? 1 : 0);
    pc = __builtin_amdgcn_readfirstlane(pc);   // wave-uniform phase -> scalar loads

    int bri = iy - i0;
    int bci = ix - j0;
    bri = min(max(bri, 0), 7);
    bci = min(max(bci, 0), 7);

    const float* wb = out + (size_t)pc * PWSTRIDE;  // uniform base (scratch in out)
    const float* pb = &patch[bri * 10 + bci];

    float a0 = 0.0f, a1 = 0.0f, a2 = 0.0f;
    #pragma unroll 2
    for (int c = 0; c < Cn; ++c) {
        // 27 wave-uniform weight loads (112B-aligned block) -> scalar s_loads
        float ww[27];
        #pragma unroll
        for (int i = 0; i < 27; ++i)
            ww[i] = wb[c * PWPAD + i];
        const float* pr = pb + c * 100;
        #pragma unroll
        for (int ky = 0; ky < 3; ++ky) {
            #pragma unroll
            for (int kx = 0; kx < 3; ++kx) {
                const float v = pr[ky * 10 + kx];
                const int   w = (ky * 3 + kx) * 3;
                a0 = fmaf(v, ww[w + 0], a0);
                a1 = fmaf(v, ww[w + 1], a1);
                a2 = fmaf(v, ww[w + 2], a2);
            }
        }
    }

    cg::this_grid().sync();   // every block done READING pw before any final write

    // ---- Stage C: final writes (clobbers scratch region with real outputs) ----
    const size_t oidx = ((size_t)bz * Qn + (size_t)Y * QWn + X) * 3;
    out[oidx + 0] = a0;
    out[oidx + 1] = a1;
    out[oidx + 2] = a2;
}

extern "C" void kernel_launch(void* const* d_in, const int* in_sizes, int n_in,
                              void* d_out, int out_size, void* d_ws, size_t ws_size,
                              hipStream_t stream) {
    const float* feat  = (const float*)d_in[0];
    const float* coord = (const float*)d_in[1];
    const float* cell  = (const float*)d_in[2];
    const float* w1    = (const float*)d_in[3];
    const float* b1    = (const float*)d_in[4];
    const float* w2    = (const float*)d_in[5];
    const float* b2    = (const float*)d_in[6];
    float* out = (float*)d_out;
    (void)d_ws; (void)ws_size;   // deliberately unused: testing ws-poison hypothesis

    void* args[] = {(void*)&feat, (void*)&coord, (void*)&cell, (void*)&w1,
                    (void*)&b1,   (void*)&w2,    (void*)&b2,   (void*)&out};
    hipLaunchCooperativeKernel((const void*)metasr_fused,
                               dim3(8, 8, 4), dim3(256, 1, 1),
                               args, 0, stream);
}

// Round 2
// 89.198 us; speedup vs baseline: 1.8552x; 1.8552x over previous
//
#include <hip/hip_runtime.h>
#include <math.h>

#define QHn 128
#define QWn 128
#define Qn  16384
#define Hn  64
#define Wn  64
#define Cn  64
#define Bn  4
#define HIDn 256
#define OUTn 1728   // C*9*3
#define PWPAD 28    // padded floats per channel (112 B, 16B-aligned stride)
#define PWSTRIDE (Cn * PWPAD)   // 1792 floats per phase
#define EPSf 1e-6f
#define PROW 12     // LDS patch row stride (floats): li*12+lj -> exactly 2-way banks (free)
#define PCH  120    // floats per channel slab (10 rows * PROW)

// Reference-faithful coordinate math (fp32, same op order/rounding as jnp).
__device__ __forceinline__ void coord_math(const float* __restrict__ coord,
                                           const float* __restrict__ cell,
                                           int b, int q,
                                           int& iy, int& ix,
                                           float& rely, float& relx, float& rrev) {
    const size_t base = ((size_t)b * Qn + q) * 2;
    const float cy = coord[base + 0];
    const float cx = coord[base + 1];
    const float ey = cell[base + 0];
    const float ex = cell[base + 1];
    const float c_y = cy - ey * 0.5f;
    const float c_x = cx - ex * 0.5f;
    const float cqy = fminf(fmaxf(c_y + EPSf, -1.0f + EPSf), 1.0f - EPSf);
    const float cqx = fminf(fmaxf(c_x + EPSf, -1.0f + EPSf), 1.0f - EPSf);
    float fy = rintf(((cqy + 1.0f) * (float)Hn - 1.0f) * 0.5f);  // round-half-even
    float fx = rintf(((cqx + 1.0f) * (float)Wn - 1.0f) * 0.5f);
    fy = fminf(fmaxf(fy, 0.0f), (float)(Hn - 1));
    fx = fminf(fmaxf(fx, 0.0f), (float)(Wn - 1));
    iy = (int)fy;
    ix = (int)fx;
    const float qcy = -1.0f + 2.0f * fy / (float)Hn;
    const float qcx = -1.0f + 2.0f * fx / (float)Wn;
    rely = (c_y - qcy) * ((float)Hn * 0.5f);
    relx = (c_x - qcx) * ((float)Wn * 0.5f);
    rrev = ey * ((float)Hn * 0.5f);
}

// Kernel 1 (unchanged from the 95.6 µs version): 4 phase-specialized pw matrices,
// padded layout pw[p*PWSTRIDE + c*PWPAD + (tap*3+o)]. grid=(27,4) block=256.
__global__ __launch_bounds__(256) void pw_kernel(
    const float* __restrict__ coord, const float* __restrict__ cell,
    const float* __restrict__ w1, const float* __restrict__ b1,
    const float* __restrict__ w2, const float* __restrict__ b2,
    float* __restrict__ pw) {
    __shared__ float hdd[HIDn];
    __shared__ float part[4 * 64];
    const int p  = blockIdx.y;          // phase 0..3 -> (py,px)
    const int py = p >> 1, px = p & 1;
    const int q  = py * QWn + px;       // representative query, batch 0

    int iy, ix; float rely, relx, rrev;
    coord_math(coord, cell, 0, q, iy, ix, rely, relx, rrev);

    const int tid = threadIdx.x;
    {   // hidden layer: thread j computes hdd[j]
        const int j = tid;
        float h = b1[j] + rely * w1[j] + relx * w1[HIDn + j] + rrev * w1[2 * HIDn + j];
        hdd[j] = fmaxf(h, 0.0f);
    }
    __syncthreads();

    const int tloc  = tid & 63;
    const int slice = tid >> 6;
    const int t     = blockIdx.x * 64 + tloc;   // 0..1727

    float s = 0.0f;
    const int j0 = slice * 64;
    #pragma unroll 16
    for (int jj = 0; jj < 64; ++jj)
        s = fmaf(hdd[j0 + jj], w2[(size_t)(j0 + jj) * OUTn + t], s);
    part[slice * 64 + tloc] = s;
    __syncthreads();

    if (tid < 64) {
        const int tt = blockIdx.x * 64 + tid;
        float v = b2[tt] + part[tid] + part[64 + tid] + part[128 + tid] + part[192 + tid];
        const int c   = tt / 27;
        const int rem = tt - c * 27;
        pw[p * PWSTRIDE + c * PWPAD + rem] = v;
    }
}

// Kernel 2 v2: per 8x8-LR tile (16x16 HR), 1024 threads = 16 waves:
// wave = (channel-group 0..3, phase 0..3); each wave does 16 channels for the
// 64 HR pixels of its phase; partials combined via small LDS buffer.
//   - occupancy: 16 waves/CU (was 4) -> 4x latency hiding
//   - patch row stride 12 (was 10): ds_read conflicts 2-way (free) instead of ~4-way
// grid=(8,8,4) block=1024.
__global__ __launch_bounds__(1024) void metasr_main(
    const float* __restrict__ feat, const float* __restrict__ coord,
    const float* __restrict__ cell, const float* __restrict__ pw,
    float* __restrict__ out) {
    __shared__ float patch[Cn * PCH];       // 64 ch * 10 rows * stride 12 = 30.7 KB
    __shared__ float part[3][256][3];       // ch-groups 1..3 partials, 9.2 KB

    const int tid = threadIdx.x;
    const int bz  = blockIdx.z;
    const int i0  = blockIdx.y * 8;         // LR tile origin
    const int j0  = blockIdx.x * 8;

    // ---- stage patch cube (zero-padded halo), padded row stride ----
    for (int e = tid; e < Cn * 100; e += 1024) {
        const int c  = e / 100;
        const int r  = e - c * 100;
        const int yy = r / 10;
        const int xx = r - yy * 10;
        const int gy = i0 - 1 + yy;
        const int gx = j0 - 1 + xx;
        float v = 0.0f;
        if ((unsigned)gy < (unsigned)Hn && (unsigned)gx < (unsigned)Wn)
            v = feat[(((size_t)bz * Cn + c) * Hn + gy) * Wn + gx];
        patch[c * PCH + yy * PROW + xx] = v;
    }
    __syncthreads();

    // ---- wave -> (channel group, phase); lane -> 8x8 LR pixel ----
    const int wv    = tid >> 6;             // 0..15
    const int phase = wv & 3;
    const int cg    = wv >> 2;              // 0..3: channels [cg*16, cg*16+16)
    const int lane  = tid & 63;
    const int li    = lane >> 3, lj = lane & 7;
    const int Y = (i0 + li) * 2 + (phase >> 1);
    const int X = (j0 + lj) * 2 + (phase & 1);

    int iy, ix; float rely, relx, rrev;
    coord_math(coord, cell, bz, Y * QWn + X, iy, ix, rely, relx, rrev);
    (void)rrev;
    int pc = ((rely > 0.25f) ? 2 : 0) + ((relx > 0.25f) ? 1 : 0);
    pc = __builtin_amdgcn_readfirstlane(pc);   // wave-uniform phase -> scalar loads

    int bri = iy - i0;
    int bci = ix - j0;
    bri = min(max(bri, 0), 7);
    bci = min(max(bci, 0), 7);

    const float* __restrict__ wb = pw + (size_t)pc * PWSTRIDE + (size_t)cg * 16 * PWPAD;
    const float* pb = &patch[cg * 16 * PCH + bri * PROW + bci];

    float a0 = 0.0f, a1 = 0.0f, a2 = 0.0f;
    #pragma unroll 2
    for (int c = 0; c < 16; ++c) {
        // 27 wave-uniform weight loads (112B-aligned block) -> scalar s_loads
        float ww[27];
        #pragma unroll
        for (int i = 0; i < 27; ++i)
            ww[i] = wb[c * PWPAD + i];
        const float* pr = pb + c * PCH;
        #pragma unroll
        for (int ky = 0; ky < 3; ++ky) {
            #pragma unroll
            for (int kx = 0; kx < 3; ++kx) {
                const float v = pr[ky * PROW + kx];
                const int   w = (ky * 3 + kx) * 3;
                a0 = fmaf(v, ww[w + 0], a0);
                a1 = fmaf(v, ww[w + 1], a1);
                a2 = fmaf(v, ww[w + 2], a2);
            }
        }
    }

    // ---- combine the 4 channel-group partials ----
    const int o = phase * 64 + lane;        // 0..255: HR pixel within tile
    if (cg != 0) {
        part[cg - 1][o][0] = a0;
        part[cg - 1][o][1] = a1;
        part[cg - 1][o][2] = a2;
    }
    __syncthreads();

    if (cg == 0) {
        a0 = ((a0 + part[0][o][0]) + part[1][o][0]) + part[2][o][0];
        a1 = ((a1 + part[0][o][1]) + part[1][o][1]) + part[2][o][1];
        a2 = ((a2 + part[0][o][2]) + part[1][o][2]) + part[2][o][2];
        const size_t oidx = ((size_t)bz * Qn + (size_t)Y * QWn + X) * 3;
        out[oidx + 0] = a0;
        out[oidx + 1] = a1;
        out[oidx + 2] = a2;
    }
}

extern "C" void kernel_launch(void* const* d_in, const int* in_sizes, int n_in,
                              void* d_out, int out_size, void* d_ws, size_t ws_size,
                              hipStream_t stream) {
    const float* feat  = (const float*)d_in[0];
    const float* coord = (const float*)d_in[1];
    const float* cell  = (const float*)d_in[2];
    const float* w1    = (const float*)d_in[3];
    const float* b1    = (const float*)d_in[4];
    const float* w2    = (const float*)d_in[5];
    const float* b2    = (const float*)d_in[6];
    float* out = (float*)d_out;
    float* pw  = (float*)d_ws;   // 4*PWSTRIDE floats = 28,672 B scratch

    pw_kernel<<<dim3(27, 4, 1), 256, 0, stream>>>(coord, cell, w1, b1, w2, b2, pw);
    metasr_main<<<dim3(8, 8, 4), 1024, 0, stream>>>(feat, coord, cell, pw, out);
}